// Round 11
// baseline (22269.295 us; speedup 1.0000x reference)
//
#include <hip/hip_runtime.h>

#define WGSZ 1024
#define NWG  64

namespace {
constexpr int kN = 2048, kH = 256, kOO = 4096, kGW = 512;
constexpr int XP = 257;                       // padded LDS row stride (floats)
// ws float offsets; slots (64 ints) at 0
constexpr int WS_CONV = 256;                  // [b][4096]
constexpr int WS_ELAH = WS_CONV + 64*kOO;     // [b][256]
constexpr int WS_ELAO = WS_ELAH + 16384;      // [i][64] index-major from here on
constexpr int WS_ELMH = WS_ELAO + 16384;
constexpr int WS_ELMO = WS_ELMH + 16384;
constexpr int WS_EBLH = WS_ELMO + 16384;
constexpr int WS_EBLO = WS_EBLH + 16384;
constexpr int WS_H0   = WS_EBLO + 16384;
constexpr int WS_C0   = WS_H0   + 16384;
constexpr int WS_H1   = WS_C0   + 16384;
constexpr int WS_C1   = WS_H1   + 16384;
constexpr int WS_G    = WS_C1   + 16384;      // [1024 rows][64]
constexpr int WS_DMH  = WS_G    + 65536;
constexpr int WS_DVH  = WS_DMH  + 16384;
}

__device__ __forceinline__ int bin_idx(float v) {
  float t = fmaf(v, 5.0f, 63.5f);
  int i0 = (int)floorf(t);
  int c0 = i0 - 1; c0 = c0 < 0 ? 0 : (c0 > 127 ? 127 : c0);
  int c1 = i0;     c1 = c1 < 0 ? 0 : (c1 > 127 ? 127 : c1);
  int c2 = i0 + 1; c2 = c2 < 0 ? 0 : (c2 > 127 ? 127 : c2);
  float d0 = fabsf(__fmul_rn(__fadd_rn((float)(c0 - 64), 0.5f), 0.2f) - v);
  float d1 = fabsf(__fmul_rn(__fadd_rn((float)(c1 - 64), 0.5f), 0.2f) - v);
  float d2 = fabsf(__fmul_rn(__fadd_rn((float)(c2 - 64), 0.5f), 0.2f) - v);
  int best = c0; float bd = d0;
  if (d1 < bd) { bd = d1; best = c1; }
  if (d2 < bd) { bd = d2; best = c2; }
  return best;
}

// numpy pairwise_sum for contiguous n=128 / 256 (exact op order).
__device__ __forceinline__ float np_pw128(const float* a) {
  float r0=a[0],r1=a[1],r2=a[2],r3=a[3],r4=a[4],r5=a[5],r6=a[6],r7=a[7];
  for (int i = 8; i < 128; i += 8) {
    r0=__fadd_rn(r0,a[i+0]); r1=__fadd_rn(r1,a[i+1]);
    r2=__fadd_rn(r2,a[i+2]); r3=__fadd_rn(r3,a[i+3]);
    r4=__fadd_rn(r4,a[i+4]); r5=__fadd_rn(r5,a[i+5]);
    r6=__fadd_rn(r6,a[i+6]); r7=__fadd_rn(r7,a[i+7]);
  }
  return __fadd_rn(__fadd_rn(__fadd_rn(r0,r1),__fadd_rn(r2,r3)),
                   __fadd_rn(__fadd_rn(r4,r5),__fadd_rn(r6,r7)));
}
__device__ __forceinline__ float np_sum256(const float* a) {
  return __fadd_rn(np_pw128(a), np_pw128(a + 128));
}
// pairwise sum of fl(d*d), d = fl(a[i]-mu) — values identical to R7's s_tmp path.
__device__ __forceinline__ float np_pw128_sq(const float* a, float mu) {
  float d;
  float r[8];
  #pragma unroll
  for (int j = 0; j < 8; ++j) { d = __fadd_rn(a[j], -mu); r[j] = __fmul_rn(d, d); }
  for (int i = 8; i < 128; i += 8) {
    #pragma unroll
    for (int j = 0; j < 8; ++j) {
      d = __fadd_rn(a[i+j], -mu);
      r[j] = __fadd_rn(r[j], __fmul_rn(d, d));
    }
  }
  return __fadd_rn(__fadd_rn(__fadd_rn(r[0],r[1]),__fadd_rn(r[2],r[3])),
                   __fadd_rn(__fadd_rn(r[4],r[5]),__fadd_rn(r[6],r[7])));
}

__device__ __forceinline__ float sig_np(float x) {
  return __fdiv_rn(1.0f, __fadd_rn(1.0f, expf(-x)));
}

// Serial ascending chain: acc[rr] += sum_i W[(r0+rr)*stride + kBase + i] * x[lane][i]
template<int R>
__device__ __forceinline__ void chain256(const float* __restrict__ W, int stride,
                                         int r0, int kBase, const float* bufX,
                                         int lane, float* acc) {
  const float* xs = bufX + lane * XP;
  #pragma unroll 4
  for (int i = 0; i < 256; ++i) {
    float xv = xs[i];
    #pragma unroll
    for (int rr = 0; rr < R; ++rr)
      acc[rr] = fmaf(W[(r0 + rr) * stride + kBase + i], xv, acc[rr]);
  }
}
template<int R>
__device__ __forceinline__ void sumchain256(const float* __restrict__ W, int stride,
                                            int r0, float* acc) {
  #pragma unroll 4
  for (int i = 0; i < 256; ++i) {
    #pragma unroll
    for (int rr = 0; rr < R; ++rr)
      acc[rr] = __fadd_rn(acc[rr], W[(r0 + rr) * stride + i]);
  }
}

// Poison-safe grid barrier over 64 WGs.
__device__ __forceinline__ void gbar(int* slots, int gen) {
  __syncthreads();
  if (threadIdx.x < 64) {
    if (threadIdx.x == 0) {
      __threadfence();
      __hip_atomic_store(&slots[blockIdx.x], gen, __ATOMIC_RELEASE, __HIP_MEMORY_SCOPE_AGENT);
    }
    for (;;) {
      int v = __hip_atomic_load(&slots[threadIdx.x], __ATOMIC_ACQUIRE, __HIP_MEMORY_SCOPE_AGENT);
      if (__all(v >= gen)) break;
      __builtin_amdgcn_s_sleep(2);
    }
    __threadfence();
  }
  __syncthreads();
}

__global__ __launch_bounds__(WGSZ, 4) void planner_kernel(
    const float* __restrict__ inp_start, const float* __restrict__ map_pts,
    const float* __restrict__ ela_w1, const float* __restrict__ ela_w2,
    const float* __restrict__ conv_w, const float* __restrict__ elm_w1,
    const float* __restrict__ elm_w2, const float* __restrict__ ebl_w1,
    const float* __restrict__ ebl_w2, const float* __restrict__ lstm_wih,
    const float* __restrict__ lstm_whh, const float* __restrict__ dm_w1,
    const float* __restrict__ dm_w2, const float* __restrict__ dv_w1,
    const float* __restrict__ dv_w2, float* __restrict__ g_out,
    float* __restrict__ ws) {
  const int wg   = blockIdx.x;        // == batch b for local phases
  const int tid  = threadIdx.x;
  const int lane = tid & 63;
  const int wv   = tid >> 6;
  int* slots = (int*)ws;
  int gen = 0;

  __shared__ __align__(16) float bufA[64 * XP];
  __shared__ __align__(16) float bufB[64 * XP];
  __shared__ unsigned s_mask[kGW];
  __shared__ float s_cw[800];
  __shared__ float s_mu[64], s_den[64];
  __shared__ float s_anchor[3], s_cs[2], s_g6[6];

  // ---- init: own-batch anchor ----
  if (tid == 0) {
    float a2 = inp_start[wg * 3 + 2];
    s_anchor[0] = inp_start[wg * 3 + 0];
    s_anchor[1] = inp_start[wg * 3 + 1];
    s_anchor[2] = a2;
    s_cs[0] = (float)cos((double)a2);
    s_cs[1] = (float)sin((double)a2);
  }
  if (tid < 3) {
    g_out[wg * 96 + tid] = inp_start[wg * 3 + tid];
    g_out[6144 + wg * 96 + tid] = 0.01f;
  }
  __syncthreads();

  const float* wsf = ws;

  for (int k = 0; k < 28; ++k) {
    const int st = k / 7, a = k % 7;
    const bool a0f = (a == 0);

    // ===== P1 (WG-local, batch b=wg): OGM + conv + ela_h — exact R7 code =====
    for (int w = tid; w < kGW; w += WGSZ) s_mask[w] = 0u;
    for (int w = tid; w < 800; w += WGSZ) s_cw[w] = conv_w[st * 800 + w];
    __syncthreads();
    {
      float ax = s_anchor[0], ay = s_anchor[1], cc = s_cs[0], ss = s_cs[1];
      for (int n = tid; n < kN; n += WGSZ) {
        float mx = __fadd_rn(map_pts[n],      -ax);
        float my = __fadd_rn(map_pts[kN + n], -ay);
        float px = fmaf(ss, my, __fmul_rn(cc, mx));
        float py = fmaf(cc, my, -__fmul_rn(ss, mx));
        bool outb = (fabsf(px) > 12.8f) || (fabsf(py) > 12.8f);
        px = outb ? 0.0f : px;
        py = outb ? 0.0f : py;
        int xi = bin_idx(px), yi = bin_idx(py);
        atomicOr(&s_mask[xi * 4 + (yi >> 5)], 1u << (yi & 31));
      }
    }
    __syncthreads();
    for (int p = tid; p < kOO; p += WGSZ) {
      int oy = p >> 6, ox = p & 63;
      unsigned occ = 0u;
      for (int ky = 0; ky < 5; ++ky) {
        int y = 2 * oy - 2 + ky;
        if ((unsigned)y >= 128u) continue;
        const unsigned* row = &s_mask[y * 4];
        for (int kx = 0; kx < 5; ++kx) {
          int x = 2 * ox - 2 + kx;
          if ((unsigned)x >= 128u) continue;
          if ((row[x >> 5] >> (x & 31)) & 1u) occ |= 1u << (ky * 5 + kx);
        }
      }
      float csum = 0.0f;
      for (int o = 0; o < 8; ++o) {
        float acc = 0.0f;
        const float* wo = s_cw + o * 100;
        for (int ci = 0; ci < 4; ++ci) {
          const float* wc = wo + ci * 25;
          #pragma unroll
          for (int t = 0; t < 25; ++t)
            if (occ & (1u << t)) acc = __fadd_rn(acc, wc[t]);
        }
        float th = tanhf(acc);
        csum = (o == 0) ? th : __fadd_rn(csum, th);
      }
      ws[WS_CONV + wg * kOO + p] = csum;
    }
    if (tid < kH) {
      const float* w1r = ela_w1 + (st * kH + tid) * 3;
      float h = fmaf(s_anchor[2], w1r[2],
                fmaf(s_anchor[1], w1r[1], __fmul_rn(s_anchor[0], w1r[0])));
      ws[WS_ELAH + wg * kH + tid] = fmaxf(h, 0.0f);
    }
    gbar(slots, ++gen);

    // ===== P2: ela_o (4 rows, wave0) + elm_h (4 rows, waves 0-1, K=4096 chunks) =====
    for (int e = tid; e < 16384; e += WGSZ) {   // stage ela_h (b-major)
      int b = e >> 8, i = e & 255;
      bufA[b * XP + i] = wsf[WS_ELAH + b * kH + i];
    }
    __syncthreads();
    if (wv == 0) {
      float acc[4] = {0,0,0,0};
      chain256<4>(ela_w2 + st * 65536, 256, wg * 4, 0, bufA, lane, acc);
      #pragma unroll
      for (int rr = 0; rr < 4; ++rr)
        ws[WS_ELAO + (wg * 4 + rr) * 64 + lane] = acc[rr];
    }
    __syncthreads();
    {
      float accE[2] = {0, 0};
      for (int c = 0; c < 16; ++c) {
        for (int e = tid; e < 16384; e += WGSZ) {  // stage conv chunk (b-major)
          int b = e >> 8, i = e & 255;
          bufA[b * XP + i] = wsf[WS_CONV + b * kOO + c * 256 + i];
        }
        __syncthreads();
        if (wv < 2)
          chain256<2>(elm_w1 + st * kH * kOO, kOO, wg * 4 + wv * 2, c * 256, bufA, lane, accE);
        __syncthreads();
      }
      if (wv < 2) {
        #pragma unroll
        for (int rr = 0; rr < 2; ++rr)
          ws[WS_ELMH + (wg * 4 + wv * 2 + rr) * 64 + lane] = fmaxf(accE[rr], 0.0f);
      }
    }
    gbar(slots, ++gen);

    // ===== P3: elm_o =====
    for (int e = tid; e < 16384; e += WGSZ) {   // stage elm_h (index-major -> transpose)
      int b = e & 63, i = e >> 6;
      bufA[b * XP + i] = wsf[WS_ELMH + i * 64 + b];
    }
    __syncthreads();
    if (wv == 0) {
      float acc[4] = {0,0,0,0};
      chain256<4>(elm_w2 + st * 65536, 256, wg * 4, 0, bufA, lane, acc);
      #pragma unroll
      for (int rr = 0; rr < 4; ++rr)
        ws[WS_ELMO + (wg * 4 + rr) * 64 + lane] = acc[rr];
    }
    gbar(slots, ++gen);

    // ===== P4: ebl_h (K=512 single chain: ela_o then elm_o) =====
    for (int e = tid; e < 16384; e += WGSZ) {
      int b = e & 63, i = e >> 6;
      bufA[b * XP + i] = wsf[WS_ELAO + i * 64 + b];
      bufB[b * XP + i] = wsf[WS_ELMO + i * 64 + b];
    }
    __syncthreads();
    if (wv == 0) {
      float acc[4] = {0,0,0,0};
      chain256<4>(ebl_w1 + st * kH * 512, 512, wg * 4, 0,   bufA, lane, acc);
      chain256<4>(ebl_w1 + st * kH * 512, 512, wg * 4, 256, bufB, lane, acc);
      #pragma unroll
      for (int rr = 0; rr < 4; ++rr)
        ws[WS_EBLH + (wg * 4 + rr) * 64 + lane] = fmaxf(acc[rr], 0.0f);
    }
    gbar(slots, ++gen);

    // ===== P5: ebl_o =====
    for (int e = tid; e < 16384; e += WGSZ) {
      int b = e & 63, i = e >> 6;
      bufA[b * XP + i] = wsf[WS_EBLH + i * 64 + b];
    }
    __syncthreads();
    if (wv == 0) {
      float acc[4] = {0,0,0,0};
      chain256<4>(ebl_w2 + st * 65536, 256, wg * 4, 0, bufA, lane, acc);
      #pragma unroll
      for (int rr = 0; rr < 4; ++rr)
        ws[WS_EBLO + (wg * 4 + rr) * 64 + lane] = acc[rr];
    }
    gbar(slots, ++gen);

    // ===== P6: LSTM0 gates: A = wih0@eblo, B = whh0@h0 (or sum), g = A+B =====
    for (int e = tid; e < 16384; e += WGSZ) {
      int b = e & 63, i = e >> 6;
      bufA[b * XP + i] = wsf[WS_EBLO + i * 64 + b];
      if (!a0f) bufB[b * XP + i] = wsf[WS_H0 + i * 64 + b];
    }
    __syncthreads();
    if (wv < 2) {
      int r0 = wg * 16 + wv * 8;
      float accA[8] = {0,0,0,0,0,0,0,0};
      float accB[8] = {0,0,0,0,0,0,0,0};
      chain256<8>(lstm_wih + (st * 2 + 0) * 1024 * 256, 256, r0, 0, bufA, lane, accA);
      if (a0f) sumchain256<8>(lstm_whh + (st * 2 + 0) * 1024 * 256, 256, r0, accB);
      else     chain256<8>(lstm_whh + (st * 2 + 0) * 1024 * 256, 256, r0, 0, bufB, lane, accB);
      #pragma unroll
      for (int rr = 0; rr < 8; ++rr)
        ws[WS_G + (r0 + rr) * 64 + lane] = __fadd_rn(accA[rr], accB[rr]);
    }
    gbar(slots, ++gen);

    // ===== P7: cell0 (j in [wg*4, wg*4+4), lane=b) =====
    if (wv < 4) {
      int j = wg * 4 + wv;
      float gi = wsf[WS_G + (0 * 256 + j) * 64 + lane];
      float gf = wsf[WS_G + (1 * 256 + j) * 64 + lane];
      float gg = wsf[WS_G + (2 * 256 + j) * 64 + lane];
      float go = wsf[WS_G + (3 * 256 + j) * 64 + lane];
      float cprev = a0f ? 1.0f : wsf[WS_C0 + j * 64 + lane];
      float cl = __fadd_rn(__fmul_rn(sig_np(gf), cprev),
                           __fmul_rn(sig_np(gi), tanhf(gg)));
      float hl = __fmul_rn(sig_np(go), tanhf(cl));
      ws[WS_C0 + j * 64 + lane] = cl;
      ws[WS_H0 + j * 64 + lane] = hl;
    }
    gbar(slots, ++gen);

    // ===== P8: LSTM1 gates =====
    for (int e = tid; e < 16384; e += WGSZ) {
      int b = e & 63, i = e >> 6;
      bufA[b * XP + i] = wsf[WS_H0 + i * 64 + b];
      if (!a0f) bufB[b * XP + i] = wsf[WS_H1 + i * 64 + b];
    }
    __syncthreads();
    if (wv < 2) {
      int r0 = wg * 16 + wv * 8;
      float accA[8] = {0,0,0,0,0,0,0,0};
      float accB[8] = {0,0,0,0,0,0,0,0};
      chain256<8>(lstm_wih + (st * 2 + 1) * 1024 * 256, 256, r0, 0, bufA, lane, accA);
      if (a0f) sumchain256<8>(lstm_whh + (st * 2 + 1) * 1024 * 256, 256, r0, accB);
      else     chain256<8>(lstm_whh + (st * 2 + 1) * 1024 * 256, 256, r0, 0, bufB, lane, accB);
      #pragma unroll
      for (int rr = 0; rr < 8; ++rr)
        ws[WS_G + (r0 + rr) * 64 + lane] = __fadd_rn(accA[rr], accB[rr]);
    }
    gbar(slots, ++gen);

    // ===== P9: cell1 =====
    if (wv < 4) {
      int j = wg * 4 + wv;
      float gi = wsf[WS_G + (0 * 256 + j) * 64 + lane];
      float gf = wsf[WS_G + (1 * 256 + j) * 64 + lane];
      float gg = wsf[WS_G + (2 * 256 + j) * 64 + lane];
      float go = wsf[WS_G + (3 * 256 + j) * 64 + lane];
      float cprev = a0f ? 1.0f : wsf[WS_C1 + j * 64 + lane];
      float cl = __fadd_rn(__fmul_rn(sig_np(gf), cprev),
                           __fmul_rn(sig_np(gi), tanhf(gg)));
      float hl = __fmul_rn(sig_np(go), tanhf(cl));
      ws[WS_C1 + j * 64 + lane] = cl;
      ws[WS_H1 + j * 64 + lane] = hl;
    }
    gbar(slots, ++gen);

    // ===== P10: LN (redundant per WG, numpy pairwise) + r + dm_h/dv_h =====
    for (int e = tid; e < 16384; e += WGSZ) {
      int b = e & 63, i = e >> 6;
      bufA[b * XP + i] = wsf[WS_H1 + i * 64 + b];
      bufB[b * XP + i] = wsf[WS_EBLO + i * 64 + b];
    }
    __syncthreads();
    if (tid < 64) {
      const float* hb = bufA + tid * XP;
      float mu = __fdiv_rn(np_sum256(hb), 256.0f);
      s_mu[tid] = mu;
      float s = __fadd_rn(np_pw128_sq(hb, mu), np_pw128_sq(hb + 128, mu));
      float v = __fdiv_rn(s, 256.0f);
      s_den[tid] = __fsqrt_rn(__fadd_rn(v, 1e-5f));
    }
    __syncthreads();
    for (int e = tid; e < 16384; e += WGSZ) {   // r in place over bufA
      int b = e >> 8, i = e & 255;
      float d = __fadd_rn(bufA[b * XP + i], -s_mu[b]);
      bufA[b * XP + i] = fmaxf(__fadd_rn(__fdiv_rn(d, s_den[b]), bufB[b * XP + i]), 0.0f);
    }
    __syncthreads();
    if (wv < 2) {
      const float* W1 = (wv == 0 ? dm_w1 : dv_w1) + st * 65536;
      float acc[4] = {0,0,0,0};
      chain256<4>(W1, 256, wg * 4, 0, bufA, lane, acc);
      int base = (wv == 0 ? WS_DMH : WS_DVH);
      #pragma unroll
      for (int rr = 0; rr < 4; ++rr)
        ws[base + (wg * 4 + rr) * 64 + lane] = fmaxf(acc[rr], 0.0f);
    }
    gbar(slots, ++gen);

    // ===== P11 (WG-local, batch b=wg): heads + anchor update + outputs =====
    if (tid < 6) {
      int d = tid % 3; bool isv = tid >= 3;
      const float* w2 = (isv ? dv_w2 : dm_w2) + (st * 3 + d) * kH;
      const float* hv = wsf + (isv ? WS_DVH : WS_DMH);
      float acc = 0.0f;
      for (int i = 0; i < kH; ++i) acc = fmaf(w2[i], hv[i * 64 + wg], acc);
      s_g6[tid] = acc;
    }
    __syncthreads();
    if (tid == 0) {
      const float dlmf[3] = {2.0f, 2.0f, 0.5f};
      for (int d = 0; d < 3; ++d) {
        float avn = __fadd_rn(s_anchor[d], __fmul_rn(tanhf(s_g6[d]), dlmf[d]));
        float vvn = __fmul_rn(sig_np(s_g6[3 + d]), 0.1f);
        s_anchor[d] = avn;
        int o = ((wg * 4 + st) * 8 + (a + 1)) * 3 + d;
        g_out[o] = avn;
        g_out[6144 + o] = vvn;
        if (a == 6 && st < 3) {
          int o2 = ((wg * 4 + st + 1) * 8 + 0) * 3 + d;
          g_out[o2] = avn;
          g_out[6144 + o2] = vvn;
        }
      }
      s_cs[0] = (float)cos((double)s_anchor[2]);
      s_cs[1] = (float)sin((double)s_anchor[2]);
    }
    __syncthreads();
  }
}

extern "C" void kernel_launch(void* const* d_in, const int* in_sizes, int n_in,
                              void* d_out, int out_size, void* d_ws, size_t ws_size,
                              hipStream_t stream) {
  (void)in_sizes; (void)n_in; (void)out_size; (void)ws_size;
  planner_kernel<<<dim3(NWG), dim3(WGSZ), 0, stream>>>(
      (const float*)d_in[0],  (const float*)d_in[1],  (const float*)d_in[2],
      (const float*)d_in[3],  (const float*)d_in[4],  (const float*)d_in[5],
      (const float*)d_in[6],  (const float*)d_in[7],  (const float*)d_in[8],
      (const float*)d_in[9],  (const float*)d_in[10], (const float*)d_in[11],
      (const float*)d_in[12], (const float*)d_in[13], (const float*)d_in[14],
      (float*)d_out, (float*)d_ws);
}

// Round 12
// 16063.022 us; speedup vs baseline: 1.3864x; 1.3864x over previous
//
#include <hip/hip_runtime.h>

#define WGSZ 1024
#define NWG  64

namespace {
constexpr int kN = 2048, kH = 256, kOO = 4096, kGW = 512;
constexpr int XP = 257;                       // padded LDS row stride (floats)
// ws float offsets; slots (64 ints) at 0 (reserve 64 floats)
constexpr int WS_CONV = 64;                   // [b][4096]
constexpr int WS_ELAH = WS_CONV + 64*kOO;     // [b][256]
constexpr int WS_ELAO = WS_ELAH + 16384;      // [r][64] row-major from here on
constexpr int WS_ELMH = WS_ELAO + 16384;
constexpr int WS_ELMO = WS_ELMH + 16384;
constexpr int WS_EBLH = WS_ELMO + 16384;
constexpr int WS_EBLO = WS_EBLH + 16384;
constexpr int WS_H0   = WS_EBLO + 16384;
constexpr int WS_C0   = WS_H0   + 16384;
constexpr int WS_H1   = WS_C0   + 16384;
constexpr int WS_C1   = WS_H1   + 16384;
constexpr int WS_G    = WS_C1   + 16384;      // [1024 rows][64]
constexpr int WS_DMH  = WS_G    + 65536;
constexpr int WS_DVH  = WS_DMH  + 16384;
}

__device__ __forceinline__ int bin_idx(float v) {
  float t = fmaf(v, 5.0f, 63.5f);
  int i0 = (int)floorf(t);
  int c0 = i0 - 1; c0 = c0 < 0 ? 0 : (c0 > 127 ? 127 : c0);
  int c1 = i0;     c1 = c1 < 0 ? 0 : (c1 > 127 ? 127 : c1);
  int c2 = i0 + 1; c2 = c2 < 0 ? 0 : (c2 > 127 ? 127 : c2);
  float d0 = fabsf(__fmul_rn(__fadd_rn((float)(c0 - 64), 0.5f), 0.2f) - v);
  float d1 = fabsf(__fmul_rn(__fadd_rn((float)(c1 - 64), 0.5f), 0.2f) - v);
  float d2 = fabsf(__fmul_rn(__fadd_rn((float)(c2 - 64), 0.5f), 0.2f) - v);
  int best = c0; float bd = d0;
  if (d1 < bd) { bd = d1; best = c1; }
  if (d2 < bd) { bd = d2; best = c2; }
  return best;
}

// numpy pairwise_sum, exact op order, contiguous n=128/256.
__device__ __forceinline__ float np_pw128(const float* a) {
  float r0=a[0],r1=a[1],r2=a[2],r3=a[3],r4=a[4],r5=a[5],r6=a[6],r7=a[7];
  for (int i = 8; i < 128; i += 8) {
    r0=__fadd_rn(r0,a[i+0]); r1=__fadd_rn(r1,a[i+1]);
    r2=__fadd_rn(r2,a[i+2]); r3=__fadd_rn(r3,a[i+3]);
    r4=__fadd_rn(r4,a[i+4]); r5=__fadd_rn(r5,a[i+5]);
    r6=__fadd_rn(r6,a[i+6]); r7=__fadd_rn(r7,a[i+7]);
  }
  return __fadd_rn(__fadd_rn(__fadd_rn(r0,r1),__fadd_rn(r2,r3)),
                   __fadd_rn(__fadd_rn(r4,r5),__fadd_rn(r6,r7)));
}
__device__ __forceinline__ float np_sum256(const float* a) {
  return __fadd_rn(np_pw128(a), np_pw128(a + 128));
}
__device__ __forceinline__ float np_pw128_sq(const float* a, float mu) {
  float d, r[8];
  #pragma unroll
  for (int j = 0; j < 8; ++j) { d = __fadd_rn(a[j], -mu); r[j] = __fmul_rn(d, d); }
  for (int i = 8; i < 128; i += 8) {
    #pragma unroll
    for (int j = 0; j < 8; ++j) {
      d = __fadd_rn(a[i+j], -mu);
      r[j] = __fadd_rn(r[j], __fmul_rn(d, d));
    }
  }
  return __fadd_rn(__fadd_rn(__fadd_rn(r[0],r[1]),__fadd_rn(r[2],r[3])),
                   __fadd_rn(__fadd_rn(r[4],r[5]),__fadd_rn(r[6],r[7])));
}

__device__ __forceinline__ float sig_np(float x) {
  return __fdiv_rn(1.0f, __fadd_rn(1.0f, expf(-x)));
}

// wave=row chain: W row uniform across lanes (broadcast), x per-lane from LDS.
__device__ __forceinline__ float chainK(const float* __restrict__ Wrow,
                                        const float* xs, int K, float acc) {
  #pragma unroll 8
  for (int i = 0; i < K; ++i) acc = fmaf(Wrow[i], xs[i], acc);
  return acc;
}

// Poison-safe grid barrier over 64 WGs (monotone gen; 0xAAAAAAAA < 1 as int).
__device__ __forceinline__ void gbar(int* slots, int gen) {
  __syncthreads();
  if (threadIdx.x < 64) {
    if (threadIdx.x == 0) {
      __threadfence();
      __hip_atomic_store(&slots[blockIdx.x], gen, __ATOMIC_RELEASE, __HIP_MEMORY_SCOPE_AGENT);
    }
    for (;;) {
      int v = __hip_atomic_load(&slots[threadIdx.x], __ATOMIC_ACQUIRE, __HIP_MEMORY_SCOPE_AGENT);
      if (__all(v >= gen)) break;
      __builtin_amdgcn_s_sleep(2);
    }
    __threadfence();
  }
  __syncthreads();
}

__global__ __launch_bounds__(WGSZ, 4) void planner_kernel(
    const float* __restrict__ inp_start, const float* __restrict__ map_pts,
    const float* __restrict__ ela_w1, const float* __restrict__ ela_w2,
    const float* __restrict__ conv_w, const float* __restrict__ elm_w1,
    const float* __restrict__ elm_w2, const float* __restrict__ ebl_w1,
    const float* __restrict__ ebl_w2, const float* __restrict__ lstm_wih,
    const float* __restrict__ lstm_whh, const float* __restrict__ dm_w1,
    const float* __restrict__ dm_w2, const float* __restrict__ dv_w1,
    const float* __restrict__ dv_w2, float* __restrict__ g_out,
    float* ws) {
  const int wg   = blockIdx.x;        // == batch b for local phases
  const int tid  = threadIdx.x;
  const int lane = tid & 63;
  const int wv   = tid >> 6;
  int* slots = (int*)ws;
  int gen = 0;

  __shared__ __align__(16) float bufA[64 * XP];
  __shared__ __align__(16) float bufB[64 * XP];
  __shared__ unsigned s_mask[kGW];
  __shared__ float s_cw[800];
  __shared__ float s_mu[64], s_den[64];
  __shared__ float s_dmhL[kH], s_dvhL[kH];
  __shared__ float s_anchor[3], s_cs[2], s_g6[6];

  if (tid == 0) {
    float a2 = inp_start[wg * 3 + 2];
    s_anchor[0] = inp_start[wg * 3 + 0];
    s_anchor[1] = inp_start[wg * 3 + 1];
    s_anchor[2] = a2;
    s_cs[0] = (float)cos((double)a2);
    s_cs[1] = (float)sin((double)a2);
  }
  if (tid < 3) {
    g_out[wg * 96 + tid] = inp_start[wg * 3 + tid];
    g_out[6144 + wg * 96 + tid] = 0.01f;
  }
  __syncthreads();

  const float* wsf = ws;

  for (int k = 0; k < 28; ++k) {
    const int st = k / 7, a = k % 7;
    const bool a0f = (a == 0);

    // ===== P1 (WG-local, batch b=wg): OGM + conv + ela_h — exact R7 code =====
    for (int w = tid; w < kGW; w += WGSZ) s_mask[w] = 0u;
    for (int w = tid; w < 800; w += WGSZ) s_cw[w] = conv_w[st * 800 + w];
    __syncthreads();
    {
      float ax = s_anchor[0], ay = s_anchor[1], cc = s_cs[0], ss = s_cs[1];
      for (int n = tid; n < kN; n += WGSZ) {
        float mx = __fadd_rn(map_pts[n],      -ax);
        float my = __fadd_rn(map_pts[kN + n], -ay);
        float px = fmaf(ss, my, __fmul_rn(cc, mx));
        float py = fmaf(cc, my, -__fmul_rn(ss, mx));
        bool outb = (fabsf(px) > 12.8f) || (fabsf(py) > 12.8f);
        px = outb ? 0.0f : px;
        py = outb ? 0.0f : py;
        int xi = bin_idx(px), yi = bin_idx(py);
        atomicOr(&s_mask[xi * 4 + (yi >> 5)], 1u << (yi & 31));
      }
    }
    __syncthreads();
    for (int p = tid; p < kOO; p += WGSZ) {
      int oy = p >> 6, ox = p & 63;
      unsigned occ = 0u;
      for (int ky = 0; ky < 5; ++ky) {
        int y = 2 * oy - 2 + ky;
        if ((unsigned)y >= 128u) continue;
        const unsigned* row = &s_mask[y * 4];
        for (int kx = 0; kx < 5; ++kx) {
          int x = 2 * ox - 2 + kx;
          if ((unsigned)x >= 128u) continue;
          if ((row[x >> 5] >> (x & 31)) & 1u) occ |= 1u << (ky * 5 + kx);
        }
      }
      float csum = 0.0f;
      for (int o = 0; o < 8; ++o) {
        float acc = 0.0f;
        const float* wo = s_cw + o * 100;
        for (int ci = 0; ci < 4; ++ci) {
          const float* wc = wo + ci * 25;
          #pragma unroll
          for (int t = 0; t < 25; ++t)
            if (occ & (1u << t)) acc = __fadd_rn(acc, wc[t]);
        }
        float th = tanhf(acc);
        csum = (o == 0) ? th : __fadd_rn(csum, th);
      }
      ws[WS_CONV + wg * kOO + p] = csum;
    }
    if (tid < kH) {
      const float* w1r = ela_w1 + (st * kH + tid) * 3;
      float h = fmaf(s_anchor[2], w1r[2],
                fmaf(s_anchor[1], w1r[1], __fmul_rn(s_anchor[0], w1r[0])));
      ws[WS_ELAH + wg * kH + tid] = fmaxf(h, 0.0f);
    }
    gbar(slots, ++gen);

    // ===== P2: ela_o (waves 0-3) + elm_h (waves 0-3, K=4096 in 16 staged chunks) =====
    for (int e = tid; e < 16384; e += WGSZ) {   // stage ela_h (b-major source)
      int b = e >> 8, i = e & 255;
      bufA[b * XP + i] = wsf[WS_ELAH + b * kH + i];
    }
    __syncthreads();
    if (wv < 4) {
      int r = wg * 4 + wv;
      float acc = chainK(ela_w2 + st * 65536 + r * 256, bufA + lane * XP, 256, 0.0f);
      ws[WS_ELAO + r * 64 + lane] = acc;
    }
    {
      float accE = 0.0f;
      for (int c = 0; c < 16; ++c) {
        __syncthreads();   // protect bufB from previous chunk's readers
        for (int e = tid; e < 16384; e += WGSZ) {
          int b = e >> 8, i = e & 255;
          bufB[b * XP + i] = wsf[WS_CONV + b * kOO + c * 256 + i];
        }
        __syncthreads();
        if (wv < 4) {
          int r = wg * 4 + wv;
          accE = chainK(elm_w1 + st * kH * kOO + r * kOO + c * 256,
                        bufB + lane * XP, 256, accE);
        }
      }
      if (wv < 4) {
        int r = wg * 4 + wv;
        ws[WS_ELMH + r * 64 + lane] = fmaxf(accE, 0.0f);
      }
    }
    gbar(slots, ++gen);

    // ===== P3: elm_o =====
    for (int e = tid; e < 16384; e += WGSZ) {   // transpose-stage [r][64] -> [b][i]
      int b = e & 63, i = e >> 6;
      bufA[b * XP + i] = wsf[WS_ELMH + i * 64 + b];
    }
    __syncthreads();
    if (wv < 4) {
      int r = wg * 4 + wv;
      float acc = chainK(elm_w2 + st * 65536 + r * 256, bufA + lane * XP, 256, 0.0f);
      ws[WS_ELMO + r * 64 + lane] = acc;
    }
    gbar(slots, ++gen);

    // ===== P4: ebl_h (K=512: ela_o then elm_o, one chain) =====
    for (int e = tid; e < 16384; e += WGSZ) {
      int b = e & 63, i = e >> 6;
      bufA[b * XP + i] = wsf[WS_ELAO + i * 64 + b];
      bufB[b * XP + i] = wsf[WS_ELMO + i * 64 + b];
    }
    __syncthreads();
    if (wv < 4) {
      int r = wg * 4 + wv;
      const float* W = ebl_w1 + st * kH * 512 + r * 512;
      float acc = chainK(W,       bufA + lane * XP, 256, 0.0f);
      acc       = chainK(W + 256, bufB + lane * XP, 256, acc);
      ws[WS_EBLH + r * 64 + lane] = fmaxf(acc, 0.0f);
    }
    gbar(slots, ++gen);

    // ===== P5: ebl_o =====
    for (int e = tid; e < 16384; e += WGSZ) {
      int b = e & 63, i = e >> 6;
      bufA[b * XP + i] = wsf[WS_EBLH + i * 64 + b];
    }
    __syncthreads();
    if (wv < 4) {
      int r = wg * 4 + wv;
      float acc = chainK(ebl_w2 + st * 65536 + r * 256, bufA + lane * XP, 256, 0.0f);
      ws[WS_EBLO + r * 64 + lane] = acc;
    }
    gbar(slots, ++gen);

    // ===== P6: LSTM0 gates (16 waves, row = wg*16+wv) =====
    for (int e = tid; e < 16384; e += WGSZ) {
      int b = e & 63, i = e >> 6;
      bufA[b * XP + i] = wsf[WS_EBLO + i * 64 + b];
      if (!a0f) bufB[b * XP + i] = wsf[WS_H0 + i * 64 + b];
    }
    __syncthreads();
    {
      int row = wg * 16 + wv;
      const float* wa = lstm_wih + (st * 2 + 0) * 262144 + row * 256;
      const float* wb = lstm_whh + (st * 2 + 0) * 262144 + row * 256;
      const float* xs1 = bufA + lane * XP;
      const float* xs2 = bufB + lane * XP;
      float A = 0.0f, B = 0.0f;
      if (a0f) {
        #pragma unroll 8
        for (int i = 0; i < 256; ++i) { A = fmaf(wa[i], xs1[i], A); B = __fadd_rn(B, wb[i]); }
      } else {
        #pragma unroll 8
        for (int i = 0; i < 256; ++i) { A = fmaf(wa[i], xs1[i], A); B = fmaf(wb[i], xs2[i], B); }
      }
      ws[WS_G + row * 64 + lane] = __fadd_rn(A, B);
    }
    gbar(slots, ++gen);

    // ===== P7: cell0 (waves 0-3, j = wg*4+wv, lane=b) =====
    if (wv < 4) {
      int j = wg * 4 + wv;
      float gi = wsf[WS_G + (0 * 256 + j) * 64 + lane];
      float gf = wsf[WS_G + (1 * 256 + j) * 64 + lane];
      float gg = wsf[WS_G + (2 * 256 + j) * 64 + lane];
      float go = wsf[WS_G + (3 * 256 + j) * 64 + lane];
      float cprev = a0f ? 1.0f : wsf[WS_C0 + j * 64 + lane];
      float cl = __fadd_rn(__fmul_rn(sig_np(gf), cprev),
                           __fmul_rn(sig_np(gi), tanhf(gg)));
      float hl = __fmul_rn(sig_np(go), tanhf(cl));
      ws[WS_C0 + j * 64 + lane] = cl;
      ws[WS_H0 + j * 64 + lane] = hl;
    }
    gbar(slots, ++gen);

    // ===== P8: LSTM1 gates =====
    for (int e = tid; e < 16384; e += WGSZ) {
      int b = e & 63, i = e >> 6;
      bufA[b * XP + i] = wsf[WS_H0 + i * 64 + b];
      if (!a0f) bufB[b * XP + i] = wsf[WS_H1 + i * 64 + b];
    }
    __syncthreads();
    {
      int row = wg * 16 + wv;
      const float* wa = lstm_wih + (st * 2 + 1) * 262144 + row * 256;
      const float* wb = lstm_whh + (st * 2 + 1) * 262144 + row * 256;
      const float* xs1 = bufA + lane * XP;
      const float* xs2 = bufB + lane * XP;
      float A = 0.0f, B = 0.0f;
      if (a0f) {
        #pragma unroll 8
        for (int i = 0; i < 256; ++i) { A = fmaf(wa[i], xs1[i], A); B = __fadd_rn(B, wb[i]); }
      } else {
        #pragma unroll 8
        for (int i = 0; i < 256; ++i) { A = fmaf(wa[i], xs1[i], A); B = fmaf(wb[i], xs2[i], B); }
      }
      ws[WS_G + row * 64 + lane] = __fadd_rn(A, B);
    }
    gbar(slots, ++gen);

    // ===== P9: cell1 =====
    if (wv < 4) {
      int j = wg * 4 + wv;
      float gi = wsf[WS_G + (0 * 256 + j) * 64 + lane];
      float gf = wsf[WS_G + (1 * 256 + j) * 64 + lane];
      float gg = wsf[WS_G + (2 * 256 + j) * 64 + lane];
      float go = wsf[WS_G + (3 * 256 + j) * 64 + lane];
      float cprev = a0f ? 1.0f : wsf[WS_C1 + j * 64 + lane];
      float cl = __fadd_rn(__fmul_rn(sig_np(gf), cprev),
                           __fmul_rn(sig_np(gi), tanhf(gg)));
      float hl = __fmul_rn(sig_np(go), tanhf(cl));
      ws[WS_C1 + j * 64 + lane] = cl;
      ws[WS_H1 + j * 64 + lane] = hl;
    }
    gbar(slots, ++gen);

    // ===== P10: LN (numpy pairwise, per-batch) + r + dm/dv =====
    for (int e = tid; e < 16384; e += WGSZ) {
      int b = e & 63, i = e >> 6;
      bufA[b * XP + i] = wsf[WS_H1 + i * 64 + b];
      bufB[b * XP + i] = wsf[WS_EBLO + i * 64 + b];
    }
    __syncthreads();
    if (tid < 64) {
      const float* hb = bufA + tid * XP;
      float mu = __fdiv_rn(np_sum256(hb), 256.0f);
      s_mu[tid] = mu;
      float s = __fadd_rn(np_pw128_sq(hb, mu), np_pw128_sq(hb + 128, mu));
      float v = __fdiv_rn(s, 256.0f);
      s_den[tid] = __fsqrt_rn(__fadd_rn(v, 1e-5f));
    }
    __syncthreads();
    for (int e = tid; e < 16384; e += WGSZ) {   // r in place over bufA
      int b = e >> 8, i = e & 255;
      float d = __fadd_rn(bufA[b * XP + i], -s_mu[b]);
      bufA[b * XP + i] = fmaxf(__fadd_rn(__fdiv_rn(d, s_den[b]), bufB[b * XP + i]), 0.0f);
    }
    __syncthreads();
    if (wv < 8) {
      int r = wg * 4 + (wv & 3);
      const float* W = ((wv < 4) ? dm_w1 : dv_w1) + st * 65536 + r * 256;
      float acc = chainK(W, bufA + lane * XP, 256, 0.0f);
      int base = (wv < 4) ? WS_DMH : WS_DVH;
      ws[base + r * 64 + lane] = fmaxf(acc, 0.0f);
    }
    gbar(slots, ++gen);

    // ===== P11 (WG-local, batch b=wg): heads + anchor + outputs =====
    if (tid < 256) s_dmhL[tid] = wsf[WS_DMH + tid * 64 + wg];
    else if (tid < 512) s_dvhL[tid - 256] = wsf[WS_DVH + (tid - 256) * 64 + wg];
    __syncthreads();
    if (tid < 6) {
      int d = tid % 3; bool isv = tid >= 3;
      const float* w2 = (isv ? dv_w2 : dm_w2) + (st * 3 + d) * kH;
      const float* hv = isv ? s_dvhL : s_dmhL;
      float acc = 0.0f;
      #pragma unroll 8
      for (int i = 0; i < kH; ++i) acc = fmaf(w2[i], hv[i], acc);
      s_g6[tid] = acc;
    }
    __syncthreads();
    if (tid == 0) {
      const float dlmf[3] = {2.0f, 2.0f, 0.5f};
      for (int d = 0; d < 3; ++d) {
        float avn = __fadd_rn(s_anchor[d], __fmul_rn(tanhf(s_g6[d]), dlmf[d]));
        float vvn = __fmul_rn(sig_np(s_g6[3 + d]), 0.1f);
        s_anchor[d] = avn;
        int o = ((wg * 4 + st) * 8 + (a + 1)) * 3 + d;
        g_out[o] = avn;
        g_out[6144 + o] = vvn;
        if (a == 6 && st < 3) {
          int o2 = ((wg * 4 + st + 1) * 8 + 0) * 3 + d;
          g_out[o2] = avn;
          g_out[6144 + o2] = vvn;
        }
      }
      s_cs[0] = (float)cos((double)s_anchor[2]);
      s_cs[1] = (float)sin((double)s_anchor[2]);
    }
    __syncthreads();
  }
}

extern "C" void kernel_launch(void* const* d_in, const int* in_sizes, int n_in,
                              void* d_out, int out_size, void* d_ws, size_t ws_size,
                              hipStream_t stream) {
  (void)in_sizes; (void)n_in; (void)out_size; (void)ws_size;
  planner_kernel<<<dim3(NWG), dim3(WGSZ), 0, stream>>>(
      (const float*)d_in[0],  (const float*)d_in[1],  (const float*)d_in[2],
      (const float*)d_in[3],  (const float*)d_in[4],  (const float*)d_in[5],
      (const float*)d_in[6],  (const float*)d_in[7],  (const float*)d_in[8],
      (const float*)d_in[9],  (const float*)d_in[10], (const float*)d_in[11],
      (const float*)d_in[12], (const float*)d_in[13], (const float*)d_in[14],
      (float*)d_out, (float*)d_ws);
}